// Round 9
// baseline (625.216 us; speedup 1.0000x reference)
//
#include <hip/hip_runtime.h>
#include <hip/hip_bf16.h>

// Problem constants. All reference dtypes float32 (proven r7+).
#define T_   2048
#define C_   768
#define NH_  12
#define HD_  64
#define M_   (2*T_)                  // 4096 rows
#define N1_  (3*C_)                  // 2304 qkv cols
#define PB_  ((size_t)NH_*T_*HD_)    // per-batch slab: 1,572,864 elems
#define KS_  0.180336880f            // 0.125 * log2(e)
#define MK_  8.65617024f             // 48 * KS_ — fixed softmax shift (r14-proven)
#define NBLK 768                     // mega grid; capacity 1024 (launch_bounds 256,4)

typedef __attribute__((ext_vector_type(8))) short  short8;   // 8 bf16
typedef __attribute__((ext_vector_type(4))) short  shortx4;  // 4 bf16
typedef __attribute__((ext_vector_type(4))) float  floatx4;

__device__ __forceinline__ floatx4 mfma_bf16(short8 a, short8 b, floatx4 c) {
    return __builtin_amdgcn_mfma_f32_16x16x32_bf16(a, b, c, 0, 0, 0);
}
__device__ __forceinline__ float fast_exp2(float x) {
    return __builtin_amdgcn_exp2f(x);
}
// v15 LDS fence (attn measured 58.4-58.8 us with and without sched_barrier).
__device__ __forceinline__ void lds_fence() {
    asm volatile("s_waitcnt lgkmcnt(0)" ::: "memory");
}
// Async global->LDS DMA, 16B/lane (m97-proven).
__device__ __forceinline__ void async_load16(const __hip_bfloat16* g, __hip_bfloat16* l) {
    __builtin_amdgcn_global_load_lds(
        (const __attribute__((address_space(1))) void*)g,
        (__attribute__((address_space(3))) void*)l, 16, 0, 0);
}

// r28: device-scope grid barrier (r27 fixed: __builtin_amdgcn_fence, not the
// nonexistent __hip_atomic_fence). Monotonic arrival counter, zeroed each launch
// by hipMemsetAsync BEFORE the kernel in the same captured stream. All blocks
// co-resident by construction: NBLK=768 <= 4 blocks/CU x 256 CU = 1024
// (launch_bounds(256,4) caps VGPR at 128; LDS 32KB -> 5/CU). "agent" fences
// give cross-XCD release/acquire around the barrier.
__device__ __forceinline__ void grid_sync(unsigned int* cnt, unsigned int target) {
    __builtin_amdgcn_fence(__ATOMIC_RELEASE, "agent");   // drain + wb my stores
    __syncthreads();
    if (threadIdx.x == 0) {
        __hip_atomic_fetch_add(cnt, 1u, __ATOMIC_RELAXED, __HIP_MEMORY_SCOPE_AGENT);
        while (__hip_atomic_load(cnt, __ATOMIC_RELAXED, __HIP_MEMORY_SCOPE_AGENT) < target)
            __builtin_amdgcn_s_sleep(2);
    }
    __syncthreads();
    __builtin_amdgcn_fence(__ATOMIC_ACQUIRE, "agent");   // inv caches before reads
}

// ---------- phase bodies as device functions (shared by mega + fallback kernels) ----------

__device__ __forceinline__ void prep_unit(unsigned u, const float* __restrict__ x,
                                          const float* __restrict__ wqkv,
                                          const float* __restrict__ wproj,
                                          __hip_bfloat16* __restrict__ xb,
                                          __hip_bfloat16* __restrict__ wqkvT,
                                          __hip_bfloat16* __restrict__ wprojT) {
    if (u < 3072u) {
        const int idx = u * 256 + threadIdx.x;
        const floatx4 v = ((const floatx4*)x)[idx];
        union { __hip_bfloat16 h[4]; shortx4 s; } w;
#pragma unroll
        for (int j = 0; j < 4; j++) w.h[j] = __float2bfloat16(v[j]);
        ((shortx4*)xb)[idx] = w.s;
    } else if (u < 3936u) {
        const int j  = (u - 3072) * 256 + threadIdx.x;  // < 221184
        const int k8 = j / N1_;
        const int n  = j - k8 * N1_;
        union { __hip_bfloat16 h[8]; short8 s; } w;
#pragma unroll
        for (int jj = 0; jj < 8; jj++)
            w.h[jj] = __float2bfloat16(wqkv[(size_t)(k8 * 8 + jj) * N1_ + n]);
        *(short8*)(wqkvT + (size_t)n * C_ + k8 * 8) = w.s;
    } else {
        const int j  = (u - 3936) * 256 + threadIdx.x;  // < 73728
        const int k8 = j / C_;
        const int n  = j - k8 * C_;
        union { __hip_bfloat16 h[8]; short8 s; } w;
#pragma unroll
        for (int jj = 0; jj < 8; jj++)
            w.h[jj] = __float2bfloat16(wproj[(size_t)(k8 * 8 + jj) * C_ + n]);
        *(short8*)(wprojT + (size_t)n * C_ + k8 * 8) = w.s;
    }
}

// gemm1: 128x128 tile, 2-phase DMA dbuf (v13 body, refcheck-passed r5). As/Bs = 16KB each.
__device__ __forceinline__ void gemm128_block(int bx, int by,
                                              const __hip_bfloat16* __restrict__ A,
                                              const __hip_bfloat16* __restrict__ Bt,
                                              int N, int K,
                                              __hip_bfloat16* __restrict__ O0,
                                              __hip_bfloat16* __restrict__ O1,
                                              __hip_bfloat16* __restrict__ O2,
                                              __hip_bfloat16* As, __hip_bfloat16* Bs) {
    const int tid  = threadIdx.x;
    const int n0   = bx * 128;
    const int m0   = by * 128;
    const int wave = tid >> 6;
    const int ln   = tid & 63;
    const int l16  = ln & 15;
    const int q4   = ln >> 4;
    const int wm   = (wave >> 1) * 64;
    const int wn   = (wave & 1) * 64;

    const int lrow = ln >> 2;
    const int loct = (ln & 3) * 8;
    const __hip_bfloat16* ApD0 = A  + (size_t)(m0 + (2 * wave)     * 16 + lrow) * K + loct;
    const __hip_bfloat16* ApD1 = A  + (size_t)(m0 + (2 * wave + 1) * 16 + lrow) * K + loct;
    const __hip_bfloat16* BpD0 = Bt + (size_t)(n0 + (2 * wave)     * 16 + lrow) * K + loct;
    const __hip_bfloat16* BpD1 = Bt + (size_t)(n0 + (2 * wave + 1) * 16 + lrow) * K + loct;

    floatx4 acc[4][4];
#pragma unroll
    for (int i = 0; i < 4; i++)
#pragma unroll
        for (int j = 0; j < 4; j++) acc[i][j] = (floatx4){0.f, 0.f, 0.f, 0.f};

    async_load16(ApD0, As + (2 * wave) * 512);
    async_load16(ApD1, As + (2 * wave + 1) * 512);
    async_load16(BpD0, Bs + (2 * wave) * 512);
    async_load16(BpD1, Bs + (2 * wave + 1) * 512);
    __syncthreads();

    const int NT = K >> 5;
    int cur = 0;
    for (int t = 0; t < NT; ++t) {
        if (t < NT - 1) {
            const int k1  = (t + 1) * 32;
            const int alt = cur ^ 1;
            async_load16(ApD0 + k1, As + alt * 4096 + (2 * wave) * 512);
            async_load16(ApD1 + k1, As + alt * 4096 + (2 * wave + 1) * 512);
            async_load16(BpD0 + k1, Bs + alt * 4096 + (2 * wave) * 512);
            async_load16(BpD1 + k1, Bs + alt * 4096 + (2 * wave + 1) * 512);
        }
        const __hip_bfloat16* Asc = As + cur * 4096;
        const __hip_bfloat16* Bsc = Bs + cur * 4096;
        short8 af[4], bfr[4];
#pragma unroll
        for (int i = 0; i < 4; i++)
            af[i] = *(const short8*)(Asc + (wm + i * 16 + l16) * 32 + q4 * 8);
#pragma unroll
        for (int j = 0; j < 4; j++)
            bfr[j] = *(const short8*)(Bsc + (wn + j * 16 + l16) * 32 + q4 * 8);
#pragma unroll
        for (int i = 0; i < 4; i++)
#pragma unroll
            for (int j = 0; j < 4; j++)
                acc[i][j] = mfma_bf16(af[i], bfr[j], acc[i][j]);
        __syncthreads();
        cur ^= 1;
    }

#pragma unroll
    for (int i = 0; i < 4; i++) {
        const int mbase = m0 + wm + i * 16 + q4 * 4;
#pragma unroll
        for (int j = 0; j < 4; j++) {
            const int n = n0 + wn + j * 16 + l16;
            const int which = n / C_;
            const int rem   = n - which * C_;
            const int h     = rem >> 6;
            const int d     = rem & 63;
#pragma unroll
            for (int r = 0; r < 4; r++) {
                const int mm = mbase + r;
                const __hip_bfloat16 hv = __float2bfloat16(acc[i][j][r]);
                const int bh = (mm >> 11) * NH_ + h;
                const int t  = mm & (T_ - 1);
                if (which == 0)      O0[((size_t)bh * T_ + t) * HD_ + d] = hv;
                else if (which == 1) O1[((size_t)bh * T_ + t) * HD_ + d] = hv;
                else                 O2[((size_t)bh * HD_ + d) * T_ + t] = hv;
            }
        }
    }
}

// gemm2: 64x64 tile, reg->LDS staging (v12 body). As/Bs = 5120B each.
__device__ __forceinline__ void gemm64_block(int bx, int by,
                                             const __hip_bfloat16* __restrict__ A,
                                             const __hip_bfloat16* __restrict__ Bt,
                                             int N, int K,
                                             float* __restrict__ O0,
                                             __hip_bfloat16* As, __hip_bfloat16* Bs) {
    const int tid  = threadIdx.x;
    const int n0   = bx * 64;
    const int m0   = by * 64;
    const int srow = tid >> 2;
    const int scol = (tid & 3) * 8;
    const int wave = tid >> 6;
    const int ln   = tid & 63;
    const int l16  = ln & 15;
    const int q4   = ln >> 4;
    const int wm   = (wave >> 1) * 32;
    const int wn   = (wave & 1) * 32;

    floatx4 acc[2][2];
#pragma unroll
    for (int i = 0; i < 2; i++)
#pragma unroll
        for (int j = 0; j < 2; j++) acc[i][j] = (floatx4){0.f, 0.f, 0.f, 0.f};

    const __hip_bfloat16* Ap = A  + (size_t)(m0 + srow) * K + scol;
    const __hip_bfloat16* Bp = Bt + (size_t)(n0 + srow) * K + scol;

    for (int k0 = 0; k0 < K; k0 += 32) {
        short8 av = *(const short8*)(Ap + k0);
        short8 bv = *(const short8*)(Bp + k0);
        __syncthreads();
        *(short8*)(As + srow * 40 + scol) = av;
        *(short8*)(Bs + srow * 40 + scol) = bv;
        __syncthreads();
        short8 af[2], bfr[2];
#pragma unroll
        for (int i = 0; i < 2; i++) {
            af[i]  = *(const short8*)(As + (wm + i * 16 + l16) * 40 + q4 * 8);
            bfr[i] = *(const short8*)(Bs + (wn + i * 16 + l16) * 40 + q4 * 8);
        }
#pragma unroll
        for (int i = 0; i < 2; i++)
#pragma unroll
            for (int j = 0; j < 2; j++)
                acc[i][j] = mfma_bf16(af[i], bfr[j], acc[i][j]);
    }

#pragma unroll
    for (int i = 0; i < 2; i++) {
        const int mbase = m0 + wm + i * 16 + q4 * 4;
#pragma unroll
        for (int j = 0; j < 2; j++) {
            const int n = n0 + wn + j * 16 + l16;
#pragma unroll
            for (int r = 0; r < 4; r++)
                O0[(size_t)(mbase + r) * N + n] = acc[i][j][r];
        }
    }
}

// attn tile body (v15, measured 58.4-58.8 us): swapped-QK, packed b64 P-stores,
// V hoist, lgkmcnt-only fences. Ends with __syncthreads so the plds arena can
// be reused by the next paired tile.
typedef __hip_bfloat16 plds_t[2][16][72];
__device__ __forceinline__ void attn_block(int bh, int i,
                                           const __hip_bfloat16* __restrict__ Q,
                                           const __hip_bfloat16* __restrict__ Kd,
                                           const __hip_bfloat16* __restrict__ Vt,
                                           __hip_bfloat16* __restrict__ O,
                                           plds_t* plds) {
    const int wid  = threadIdx.x >> 6;
    const int lane = threadIdx.x & 63;
    const int l16  = lane & 15;
    const int q4   = lane >> 4;
    const int q0A  = 32 * i;
    const int q0B  = 32 * i + 16;
    const int nch  = (i >> 1) + 1;

    const __hip_bfloat16* Qh = Q  + (size_t)bh * T_ * HD_;
    const __hip_bfloat16* Kh = Kd + (size_t)bh * T_ * HD_;
    const __hip_bfloat16* Vh = Vt + (size_t)bh * HD_ * T_;

    short8 aqA[2], aqB[2];
#pragma unroll
    for (int kt = 0; kt < 2; kt++) {
        aqA[kt] = *(const short8*)(Qh + (size_t)(q0A + l16) * HD_ + kt * 32 + q4 * 8);
        aqB[kt] = *(const short8*)(Qh + (size_t)(q0B + l16) * HD_ + kt * 32 + q4 * 8);
    }

    floatx4 accA[4], accB[4];
#pragma unroll
    for (int ct = 0; ct < 4; ct++) {
        accA[ct] = (floatx4){0.f, 0.f, 0.f, 0.f};
        accB[ct] = (floatx4){0.f, 0.f, 0.f, 0.f};
    }
    float sumA = 0.f, sumB = 0.f;

    for (int c = wid; c < nch; c += 4) {
        const int kv0 = c * 64;
        const bool diag = (c == nch - 1);

        short8 bk[4][2];
#pragma unroll
        for (int nt = 0; nt < 4; nt++)
#pragma unroll
            for (int kt = 0; kt < 2; kt++)
                bk[nt][kt] = *(const short8*)(Kh + (size_t)(kv0 + nt * 16 + l16) * HD_ + kt * 32 + q4 * 8);

        short8 bv[4][2];
#pragma unroll
        for (int ct = 0; ct < 4; ct++)
#pragma unroll
            for (int kt = 0; kt < 2; kt++)
                bv[ct][kt] = *(const short8*)(Vh + (size_t)(ct * 16 + l16) * T_ + kv0 + kt * 32 + q4 * 8);

        floatx4 sA[4], sB[4];
#pragma unroll
        for (int nt = 0; nt < 4; nt++) {
            sA[nt] = (floatx4){0.f, 0.f, 0.f, 0.f};
            sB[nt] = (floatx4){0.f, 0.f, 0.f, 0.f};
#pragma unroll
            for (int kt = 0; kt < 2; kt++) {
                sA[nt] = mfma_bf16(bk[nt][kt], aqA[kt], sA[nt]);
                sB[nt] = mfma_bf16(bk[nt][kt], aqB[kt], sB[nt]);
            }
        }

        if (diag) {
#pragma unroll
            for (int nt = 0; nt < 4; nt++) {
#pragma unroll
                for (int r = 0; r < 4; r++) {
                    const int kvg = kv0 + nt * 16 + q4 * 4 + r;
                    if (kvg > q0A + l16) sA[nt][r] = -3e38f;
                    if (kvg > q0B + l16) sB[nt][r] = -3e38f;
                }
            }
        }

#pragma unroll
        for (int nt = 0; nt < 4; nt++) {
            union { __hip_bfloat16 h[4]; shortx4 s; } uA, uB;
            float pA[4], pB[4];
#pragma unroll
            for (int r = 0; r < 4; r++) {
                pA[r] = fast_exp2(sA[nt][r] * KS_ - MK_);
                pB[r] = fast_exp2(sB[nt][r] * KS_ - MK_);
                uA.h[r] = __float2bfloat16(pA[r]);
                uB.h[r] = __float2bfloat16(pB[r]);
            }
            sumA += (pA[0] + pA[1]) + (pA[2] + pA[3]);
            sumB += (pB[0] + pB[1]) + (pB[2] + pB[3]);
            *(shortx4*)(&plds[wid][0][l16][nt * 16 + q4 * 4]) = uA.s;
            *(shortx4*)(&plds[wid][1][l16][nt * 16 + q4 * 4]) = uB.s;
        }

        lds_fence();

        short8 apA[2], apB[2];
#pragma unroll
        for (int kt = 0; kt < 2; kt++) {
            apA[kt] = *(const short8*)(&plds[wid][0][l16][kt * 32 + q4 * 8]);
            apB[kt] = *(const short8*)(&plds[wid][1][l16][kt * 32 + q4 * 8]);
        }
#pragma unroll
        for (int ct = 0; ct < 4; ct++)
#pragma unroll
            for (int kt = 0; kt < 2; kt++) {
                accA[ct] = mfma_bf16(apA[kt], bv[ct][kt], accA[ct]);
                accB[ct] = mfma_bf16(apB[kt], bv[ct][kt], accB[ct]);
            }

        lds_fence();
    }

    sumA += __shfl_xor(sumA, 16, 64);
    sumA += __shfl_xor(sumA, 32, 64);
    sumB += __shfl_xor(sumB, 16, 64);
    sumB += __shfl_xor(sumB, 32, 64);

    __syncthreads();                               // plds dead; overlay arena
    floatx4* accbuf = (floatx4*)&plds[0][0][0][0];
    float*   lbuf   = (float*)((char*)&plds[0][0][0][0] + 16384);

    auto publish = [&](int slot) {
#pragma unroll
        for (int ct = 0; ct < 4; ct++) {
            accbuf[((slot * 2 + 0) * 4 + ct) * 64 + lane] = accA[ct];
            accbuf[((slot * 2 + 1) * 4 + ct) * 64 + lane] = accB[ct];
        }
        if (q4 == 0) {
            lbuf[(slot * 2 + 0) * 16 + l16] = sumA;
            lbuf[(slot * 2 + 1) * 16 + l16] = sumB;
        }
    };
    auto mergeIn = [&](int slot) {
#pragma unroll
        for (int ct = 0; ct < 4; ct++) {
            accA[ct] += accbuf[((slot * 2 + 0) * 4 + ct) * 64 + lane];
            accB[ct] += accbuf[((slot * 2 + 1) * 4 + ct) * 64 + lane];
        }
        sumA += lbuf[(slot * 2 + 0) * 16 + l16];
        sumB += lbuf[(slot * 2 + 1) * 16 + l16];
    };

    if (wid >= 2) publish(wid - 2);
    __syncthreads();
    if (wid < 2) mergeIn(wid);
    __syncthreads();
    if (wid == 1) publish(0);
    __syncthreads();
    if (wid == 0) {
        mergeIn(0);
        const int orow0 = (bh / NH_) * T_;
        const int hcol  = (bh % NH_) * HD_;
#pragma unroll
        for (int r = 0; r < 4; r++) {
            const float invA = 1.0f / __shfl(sumA, q4 * 4 + r, 64);
            const float invB = 1.0f / __shfl(sumB, q4 * 4 + r, 64);
            __hip_bfloat16* oA = O + (size_t)(orow0 + q0A + q4 * 4 + r) * C_ + hcol;
            __hip_bfloat16* oB = O + (size_t)(orow0 + q0B + q4 * 4 + r) * C_ + hcol;
#pragma unroll
            for (int ct = 0; ct < 4; ct++) {
                oA[ct * 16 + l16] = __float2bfloat16(accA[ct][r] * invA);
                oB[ct * 16 + l16] = __float2bfloat16(accB[ct][r] * invB);
            }
        }
    }
    __syncthreads();   // arena free for next paired tile
}

// ---------- r28 mega-kernel: 4 stages, 3 device-scope barriers, ONE dispatch ----------
__global__ __launch_bounds__(256, 4) void mega(const float* __restrict__ x,
                                               const float* __restrict__ wqkv,
                                               const float* __restrict__ wproj,
                                               __hip_bfloat16* __restrict__ xb,
                                               __hip_bfloat16* __restrict__ wqkvT,
                                               __hip_bfloat16* __restrict__ wprojT,
                                               __hip_bfloat16* __restrict__ Qall,
                                               __hip_bfloat16* __restrict__ Kall,
                                               __hip_bfloat16* __restrict__ Vt,
                                               __hip_bfloat16* __restrict__ ATT,
                                               float* __restrict__ out,
                                               unsigned int* cnt) {
    __shared__ __align__(16) char arena[32768];

    // phase 0: prep (4224 units, grid-stride)
    for (unsigned u = blockIdx.x; u < 4224u; u += NBLK)
        prep_unit(u, x, wqkv, wproj, xb, wqkvT, wprojT);
    grid_sync(cnt, 1u * NBLK);

    // phase 1: qkv gemm — 576 x (128x128) units, one per block
    if (blockIdx.x < 576u) {
        gemm128_block((int)(blockIdx.x % 18u), (int)(blockIdx.x / 18u),
                      xb, wqkvT, N1_, C_, Qall, Kall, Vt,
                      (__hip_bfloat16*)arena, (__hip_bfloat16*)(arena + 16384));
    }
    grid_sync(cnt, 2u * NBLK);

    // phase 2: attention — pair-balanced units (b, 1535-b): 33 chunks every block
    {
        plds_t* plds = (plds_t*)arena;
        const unsigned u1 = blockIdx.x, u2 = 1535u - blockIdx.x;
        attn_block((int)(u1 % 24u), 63 - (int)(u1 / 24u), Qall, Kall, Vt, ATT, plds);
        attn_block((int)(u2 % 24u), 63 - (int)(u2 / 24u), Qall, Kall, Vt, ATT, plds);
    }
    grid_sync(cnt, 3u * NBLK);

    // phase 3: out proj — 768 x (64x64) units, exactly one per block
    gemm64_block((int)(blockIdx.x % 12u), (int)(blockIdx.x / 12u),
                 ATT, wprojT, C_, C_, out,
                 (__hip_bfloat16*)arena, (__hip_bfloat16*)(arena + 5120));
}

// ---------- fallback-path kernels (thin wrappers; unchanged behavior) ----------
__global__ __launch_bounds__(256) void prep1(const float* __restrict__ x,
                                             const float* __restrict__ wqkv,
                                             __hip_bfloat16* __restrict__ xb,
                                             __hip_bfloat16* __restrict__ wqkvT) {
    if (blockIdx.x < 3072) {
        const int idx = blockIdx.x * 256 + threadIdx.x;
        const floatx4 v = ((const floatx4*)x)[idx];
        union { __hip_bfloat16 h[4]; shortx4 s; } u;
#pragma unroll
        for (int j = 0; j < 4; j++) u.h[j] = __float2bfloat16(v[j]);
        ((shortx4*)xb)[idx] = u.s;
    } else {
        const int j  = (blockIdx.x - 3072) * 256 + threadIdx.x;
        const int k8 = j / N1_;
        const int n  = j - k8 * N1_;
        union { __hip_bfloat16 h[8]; short8 s; } u;
#pragma unroll
        for (int jj = 0; jj < 8; jj++)
            u.h[jj] = __float2bfloat16(wqkv[(size_t)(k8 * 8 + jj) * N1_ + n]);
        *(short8*)(wqkvT + (size_t)n * C_ + k8 * 8) = u.s;
    }
}
__global__ __launch_bounds__(256) void prep2(const float* __restrict__ wproj,
                                             __hip_bfloat16* __restrict__ wprojT) {
    const int j  = blockIdx.x * 256 + threadIdx.x;
    const int k8 = j / C_;
    const int n  = j - k8 * C_;
    union { __hip_bfloat16 h[8]; short8 s; } u;
#pragma unroll
    for (int jj = 0; jj < 8; jj++)
        u.h[jj] = __float2bfloat16(wproj[(size_t)(k8 * 8 + jj) * C_ + n]);
    *(short8*)(wprojT + (size_t)n * C_ + k8 * 8) = u.s;
}
__global__ __launch_bounds__(256) void gemm_bt128(const __hip_bfloat16* __restrict__ A,
                                                  const __hip_bfloat16* __restrict__ Bt,
                                                  int N, int K,
                                                  __hip_bfloat16* __restrict__ O0,
                                                  __hip_bfloat16* __restrict__ O1,
                                                  __hip_bfloat16* __restrict__ O2) {
    __shared__ __align__(16) char ar[32768];
    gemm128_block(blockIdx.x, blockIdx.y, A, Bt, N, K, O0, O1, O2,
                  (__hip_bfloat16*)ar, (__hip_bfloat16*)(ar + 16384));
}
__global__ __launch_bounds__(256) void gemm_bt64(const __hip_bfloat16* __restrict__ A,
                                                 const __hip_bfloat16* __restrict__ Bt,
                                                 int N, int K,
                                                 float* __restrict__ O0) {
    __shared__ __align__(16) char ar[10240];
    gemm64_block(blockIdx.x, blockIdx.y, A, Bt, N, K, O0,
                 (__hip_bfloat16*)ar, (__hip_bfloat16*)(ar + 5120));
}
__global__ __launch_bounds__(256) void attn_fused(const __hip_bfloat16* __restrict__ Q,
                                                  const __hip_bfloat16* __restrict__ Kd,
                                                  const __hip_bfloat16* __restrict__ Vt,
                                                  __hip_bfloat16* __restrict__ O) {
    __shared__ __align__(16) char ar[18432];
    attn_block(blockIdx.x, 63 - (int)blockIdx.y, Q, Kd, Vt, O, (plds_t*)ar);
}

extern "C" void kernel_launch(void* const* d_in, const int* in_sizes, int n_in,
                              void* d_out, int out_size, void* d_ws, size_t ws_size,
                              hipStream_t stream) {
    const float *x = nullptr, *wqkv = nullptr, *wproj = nullptr;
    for (int i = 0; i < n_in; i++) {
        const int s = in_sizes[i];
        if (s == M_ * C_ && !x) x = (const float*)d_in[i];
        else if (s == C_ * N1_ && !wqkv) wqkv = (const float*)d_in[i];
        else if (s == C_ * C_ && !wproj) wproj = (const float*)d_in[i];
    }
    float* out = (float*)d_out;
    __hip_bfloat16* ws = (__hip_bfloat16*)d_ws;
    __hip_bfloat16* Vt = (__hip_bfloat16*)d_out;       // d_out lower half (bf16)

    // r13/14-proven aliasing chain within ws + d_out.
    __hip_bfloat16* Qall  = ws;
    __hip_bfloat16* Kall  = Qall + 2 * PB_;
    __hip_bfloat16* ATT   = Kall + 2 * PB_;
    __hip_bfloat16* xb    = ATT;
    __hip_bfloat16* wqkvT = (__hip_bfloat16*)d_out + 2 * PB_;

    const size_t needMerged = (6 * PB_ + (size_t)C_ * C_) * sizeof(__hip_bfloat16);  // 20,054,016
    if (ws_size >= needMerged) {   // r19-proven: this path runs (ws >= 20.05 MB)
        __hip_bfloat16* wprojT = ws + 6 * PB_;
        // barrier counter in the LAST 64B of d_out: untouched by Vt/wqkvT/ATT,
        // overwritten by phase-3 output only AFTER the final barrier; re-zeroed
        // here every launch (hipMemsetAsync is graph-capture-safe).
        unsigned int* cnt = (unsigned int*)((char*)d_out + (size_t)M_ * C_ * 4 - 64);
        (void)hipMemsetAsync(cnt, 0, 64, stream);
        mega<<<dim3(NBLK), 256, 0, stream>>>(x, wqkv, wproj, xb, wqkvT, wprojT,
                                             Qall, Kall, Vt, ATT, out, cnt);
    } else {
        __hip_bfloat16* wprojT = Qall;
        prep1<<<dim3(3936), 256, 0, stream>>>(x, wqkv, xb, wqkvT);
        gemm_bt128<<<dim3(N1_ / 128, M_ / 128), 256, 0, stream>>>(
            xb, wqkvT, N1_, C_, Qall, Kall, Vt);
        attn_fused<<<dim3(2 * NH_, 64), 256, 0, stream>>>(Qall, Kall, Vt, ATT);
        prep2<<<dim3(288), 256, 0, stream>>>(wproj, wprojT);
        gemm_bt64<<<dim3(C_ / 64, M_ / 64), 256, 0, stream>>>(ATT, wprojT, C_, C_, out);
    }
}

// Round 10
// 623.282 us; speedup vs baseline: 1.0031x; 1.0031x over previous
//
#include <hip/hip_runtime.h>
#include <hip/hip_bf16.h>

// Problem constants. All reference dtypes float32 (proven r7+).
#define T_   2048
#define C_   768
#define NH_  12
#define HD_  64
#define M_   (2*T_)                  // 4096 rows
#define N1_  (3*C_)                  // 2304 qkv cols
#define PB_  ((size_t)NH_*T_*HD_)    // per-batch slab: 1,572,864 elems
#define KS_  0.180336880f            // 0.125 * log2(e)
#define MK_  8.65617024f             // 48 * KS_ — fixed softmax shift (r14-proven)
#define NBLK 768                     // mega grid == guaranteed capacity (3 blocks/CU x 256)

typedef __attribute__((ext_vector_type(8))) short  short8;   // 8 bf16
typedef __attribute__((ext_vector_type(4))) short  shortx4;  // 4 bf16
typedef __attribute__((ext_vector_type(4))) float  floatx4;

__device__ __forceinline__ floatx4 mfma_bf16(short8 a, short8 b, floatx4 c) {
    return __builtin_amdgcn_mfma_f32_16x16x32_bf16(a, b, c, 0, 0, 0);
}
__device__ __forceinline__ float fast_exp2(float x) {
    return __builtin_amdgcn_exp2f(x);
}
// v15 LDS fence (attn measured 58.4-58.8 us with and without sched_barrier).
__device__ __forceinline__ void lds_fence() {
    asm volatile("s_waitcnt lgkmcnt(0)" ::: "memory");
}
// Async global->LDS DMA, 16B/lane (m97-proven).
__device__ __forceinline__ void async_load16(const __hip_bfloat16* g, __hip_bfloat16* l) {
    __builtin_amdgcn_global_load_lds(
        (const __attribute__((address_space(1))) void*)g,
        (__attribute__((address_space(3))) void*)l, 16, 0, 0);
}

// r29: device-scope grid barrier (logic verified correct in r28 — absmax clean,
// no hang). Monotonic arrival counter, zeroed each launch by hipMemsetAsync.
// r28 FAILURE CAUSE: launch_bounds(256,4) capped arch VGPRs at 64 -> every
// phase spilled to scratch (WRITE_SIZE 95MB vs 48MB expected, 554us). r29 uses
// (256,3): VGPR cap ~170 fits gemm128 (~144 incl unified AGPR acc) and attn
// (~108) spill-free, and still guarantees 3 blocks/CU -> 768 co-resident
// (LDS 3x32KB=96KB <= 160KB).
__device__ __forceinline__ void grid_sync(unsigned int* cnt, unsigned int target) {
    __builtin_amdgcn_fence(__ATOMIC_RELEASE, "agent");   // drain + wb my stores
    __syncthreads();
    if (threadIdx.x == 0) {
        __hip_atomic_fetch_add(cnt, 1u, __ATOMIC_RELAXED, __HIP_MEMORY_SCOPE_AGENT);
        while (__hip_atomic_load(cnt, __ATOMIC_RELAXED, __HIP_MEMORY_SCOPE_AGENT) < target)
            __builtin_amdgcn_s_sleep(2);
    }
    __syncthreads();
    __builtin_amdgcn_fence(__ATOMIC_ACQUIRE, "agent");   // inv caches before reads
}

// ---------- phase bodies as device functions (shared by mega + fallback kernels) ----------

__device__ __forceinline__ void prep_unit(unsigned u, const float* __restrict__ x,
                                          const float* __restrict__ wqkv,
                                          const float* __restrict__ wproj,
                                          __hip_bfloat16* __restrict__ xb,
                                          __hip_bfloat16* __restrict__ wqkvT,
                                          __hip_bfloat16* __restrict__ wprojT) {
    if (u < 3072u) {
        const int idx = u * 256 + threadIdx.x;
        const floatx4 v = ((const floatx4*)x)[idx];
        union { __hip_bfloat16 h[4]; shortx4 s; } w;
#pragma unroll
        for (int j = 0; j < 4; j++) w.h[j] = __float2bfloat16(v[j]);
        ((shortx4*)xb)[idx] = w.s;
    } else if (u < 3936u) {
        const int j  = (u - 3072) * 256 + threadIdx.x;  // < 221184
        const int k8 = j / N1_;
        const int n  = j - k8 * N1_;
        union { __hip_bfloat16 h[8]; short8 s; } w;
#pragma unroll
        for (int jj = 0; jj < 8; jj++)
            w.h[jj] = __float2bfloat16(wqkv[(size_t)(k8 * 8 + jj) * N1_ + n]);
        *(short8*)(wqkvT + (size_t)n * C_ + k8 * 8) = w.s;
    } else {
        const int j  = (u - 3936) * 256 + threadIdx.x;  // < 73728
        const int k8 = j / C_;
        const int n  = j - k8 * C_;
        union { __hip_bfloat16 h[8]; short8 s; } w;
#pragma unroll
        for (int jj = 0; jj < 8; jj++)
            w.h[jj] = __float2bfloat16(wproj[(size_t)(k8 * 8 + jj) * C_ + n]);
        *(short8*)(wprojT + (size_t)n * C_ + k8 * 8) = w.s;
    }
}

// gemm1: 128x128 tile, 2-phase DMA dbuf (v13 body, refcheck-passed r5). As/Bs = 16KB each.
__device__ __forceinline__ void gemm128_block(int bx, int by,
                                              const __hip_bfloat16* __restrict__ A,
                                              const __hip_bfloat16* __restrict__ Bt,
                                              int N, int K,
                                              __hip_bfloat16* __restrict__ O0,
                                              __hip_bfloat16* __restrict__ O1,
                                              __hip_bfloat16* __restrict__ O2,
                                              __hip_bfloat16* As, __hip_bfloat16* Bs) {
    const int tid  = threadIdx.x;
    const int n0   = bx * 128;
    const int m0   = by * 128;
    const int wave = tid >> 6;
    const int ln   = tid & 63;
    const int l16  = ln & 15;
    const int q4   = ln >> 4;
    const int wm   = (wave >> 1) * 64;
    const int wn   = (wave & 1) * 64;

    const int lrow = ln >> 2;
    const int loct = (ln & 3) * 8;
    const __hip_bfloat16* ApD0 = A  + (size_t)(m0 + (2 * wave)     * 16 + lrow) * K + loct;
    const __hip_bfloat16* ApD1 = A  + (size_t)(m0 + (2 * wave + 1) * 16 + lrow) * K + loct;
    const __hip_bfloat16* BpD0 = Bt + (size_t)(n0 + (2 * wave)     * 16 + lrow) * K + loct;
    const __hip_bfloat16* BpD1 = Bt + (size_t)(n0 + (2 * wave + 1) * 16 + lrow) * K + loct;

    floatx4 acc[4][4];
#pragma unroll
    for (int i = 0; i < 4; i++)
#pragma unroll
        for (int j = 0; j < 4; j++) acc[i][j] = (floatx4){0.f, 0.f, 0.f, 0.f};

    async_load16(ApD0, As + (2 * wave) * 512);
    async_load16(ApD1, As + (2 * wave + 1) * 512);
    async_load16(BpD0, Bs + (2 * wave) * 512);
    async_load16(BpD1, Bs + (2 * wave + 1) * 512);
    __syncthreads();

    const int NT = K >> 5;
    int cur = 0;
    for (int t = 0; t < NT; ++t) {
        if (t < NT - 1) {
            const int k1  = (t + 1) * 32;
            const int alt = cur ^ 1;
            async_load16(ApD0 + k1, As + alt * 4096 + (2 * wave) * 512);
            async_load16(ApD1 + k1, As + alt * 4096 + (2 * wave + 1) * 512);
            async_load16(BpD0 + k1, Bs + alt * 4096 + (2 * wave) * 512);
            async_load16(BpD1 + k1, Bs + alt * 4096 + (2 * wave + 1) * 512);
        }
        const __hip_bfloat16* Asc = As + cur * 4096;
        const __hip_bfloat16* Bsc = Bs + cur * 4096;
        short8 af[4], bfr[4];
#pragma unroll
        for (int i = 0; i < 4; i++)
            af[i] = *(const short8*)(Asc + (wm + i * 16 + l16) * 32 + q4 * 8);
#pragma unroll
        for (int j = 0; j < 4; j++)
            bfr[j] = *(const short8*)(Bsc + (wn + j * 16 + l16) * 32 + q4 * 8);
#pragma unroll
        for (int i = 0; i < 4; i++)
#pragma unroll
            for (int j = 0; j < 4; j++)
                acc[i][j] = mfma_bf16(af[i], bfr[j], acc[i][j]);
        __syncthreads();
        cur ^= 1;
    }

#pragma unroll
    for (int i = 0; i < 4; i++) {
        const int mbase = m0 + wm + i * 16 + q4 * 4;
#pragma unroll
        for (int j = 0; j < 4; j++) {
            const int n = n0 + wn + j * 16 + l16;
            const int which = n / C_;
            const int rem   = n - which * C_;
            const int h     = rem >> 6;
            const int d     = rem & 63;
#pragma unroll
            for (int r = 0; r < 4; r++) {
                const int mm = mbase + r;
                const __hip_bfloat16 hv = __float2bfloat16(acc[i][j][r]);
                const int bh = (mm >> 11) * NH_ + h;
                const int t  = mm & (T_ - 1);
                if (which == 0)      O0[((size_t)bh * T_ + t) * HD_ + d] = hv;
                else if (which == 1) O1[((size_t)bh * T_ + t) * HD_ + d] = hv;
                else                 O2[((size_t)bh * HD_ + d) * T_ + t] = hv;
            }
        }
    }
}

// gemm2: 64x64 tile, reg->LDS staging (v12 body). As/Bs = 5120B each.
__device__ __forceinline__ void gemm64_block(int bx, int by,
                                             const __hip_bfloat16* __restrict__ A,
                                             const __hip_bfloat16* __restrict__ Bt,
                                             int N, int K,
                                             float* __restrict__ O0,
                                             __hip_bfloat16* As, __hip_bfloat16* Bs) {
    const int tid  = threadIdx.x;
    const int n0   = bx * 64;
    const int m0   = by * 64;
    const int srow = tid >> 2;
    const int scol = (tid & 3) * 8;
    const int wave = tid >> 6;
    const int ln   = tid & 63;
    const int l16  = ln & 15;
    const int q4   = ln >> 4;
    const int wm   = (wave >> 1) * 32;
    const int wn   = (wave & 1) * 32;

    floatx4 acc[2][2];
#pragma unroll
    for (int i = 0; i < 2; i++)
#pragma unroll
        for (int j = 0; j < 2; j++) acc[i][j] = (floatx4){0.f, 0.f, 0.f, 0.f};

    const __hip_bfloat16* Ap = A  + (size_t)(m0 + srow) * K + scol;
    const __hip_bfloat16* Bp = Bt + (size_t)(n0 + srow) * K + scol;

    for (int k0 = 0; k0 < K; k0 += 32) {
        short8 av = *(const short8*)(Ap + k0);
        short8 bv = *(const short8*)(Bp + k0);
        __syncthreads();
        *(short8*)(As + srow * 40 + scol) = av;
        *(short8*)(Bs + srow * 40 + scol) = bv;
        __syncthreads();
        short8 af[2], bfr[2];
#pragma unroll
        for (int i = 0; i < 2; i++) {
            af[i]  = *(const short8*)(As + (wm + i * 16 + l16) * 40 + q4 * 8);
            bfr[i] = *(const short8*)(Bs + (wn + i * 16 + l16) * 40 + q4 * 8);
        }
#pragma unroll
        for (int i = 0; i < 2; i++)
#pragma unroll
            for (int j = 0; j < 2; j++)
                acc[i][j] = mfma_bf16(af[i], bfr[j], acc[i][j]);
    }

#pragma unroll
    for (int i = 0; i < 2; i++) {
        const int mbase = m0 + wm + i * 16 + q4 * 4;
#pragma unroll
        for (int j = 0; j < 2; j++) {
            const int n = n0 + wn + j * 16 + l16;
#pragma unroll
            for (int r = 0; r < 4; r++)
                O0[(size_t)(mbase + r) * N + n] = acc[i][j][r];
        }
    }
}

// attn tile body (v15, measured 58.4-58.8 us): swapped-QK, packed b64 P-stores,
// V hoist, lgkmcnt-only fences. Ends with __syncthreads so the plds arena can
// be reused by the next paired tile.
typedef __hip_bfloat16 plds_t[2][16][72];
__device__ __forceinline__ void attn_block(int bh, int i,
                                           const __hip_bfloat16* __restrict__ Q,
                                           const __hip_bfloat16* __restrict__ Kd,
                                           const __hip_bfloat16* __restrict__ Vt,
                                           __hip_bfloat16* __restrict__ O,
                                           plds_t* plds) {
    const int wid  = threadIdx.x >> 6;
    const int lane = threadIdx.x & 63;
    const int l16  = lane & 15;
    const int q4   = lane >> 4;
    const int q0A  = 32 * i;
    const int q0B  = 32 * i + 16;
    const int nch  = (i >> 1) + 1;

    const __hip_bfloat16* Qh = Q  + (size_t)bh * T_ * HD_;
    const __hip_bfloat16* Kh = Kd + (size_t)bh * T_ * HD_;
    const __hip_bfloat16* Vh = Vt + (size_t)bh * HD_ * T_;

    short8 aqA[2], aqB[2];
#pragma unroll
    for (int kt = 0; kt < 2; kt++) {
        aqA[kt] = *(const short8*)(Qh + (size_t)(q0A + l16) * HD_ + kt * 32 + q4 * 8);
        aqB[kt] = *(const short8*)(Qh + (size_t)(q0B + l16) * HD_ + kt * 32 + q4 * 8);
    }

    floatx4 accA[4], accB[4];
#pragma unroll
    for (int ct = 0; ct < 4; ct++) {
        accA[ct] = (floatx4){0.f, 0.f, 0.f, 0.f};
        accB[ct] = (floatx4){0.f, 0.f, 0.f, 0.f};
    }
    float sumA = 0.f, sumB = 0.f;

    for (int c = wid; c < nch; c += 4) {
        const int kv0 = c * 64;
        const bool diag = (c == nch - 1);

        short8 bk[4][2];
#pragma unroll
        for (int nt = 0; nt < 4; nt++)
#pragma unroll
            for (int kt = 0; kt < 2; kt++)
                bk[nt][kt] = *(const short8*)(Kh + (size_t)(kv0 + nt * 16 + l16) * HD_ + kt * 32 + q4 * 8);

        short8 bv[4][2];
#pragma unroll
        for (int ct = 0; ct < 4; ct++)
#pragma unroll
            for (int kt = 0; kt < 2; kt++)
                bv[ct][kt] = *(const short8*)(Vh + (size_t)(ct * 16 + l16) * T_ + kv0 + kt * 32 + q4 * 8);

        floatx4 sA[4], sB[4];
#pragma unroll
        for (int nt = 0; nt < 4; nt++) {
            sA[nt] = (floatx4){0.f, 0.f, 0.f, 0.f};
            sB[nt] = (floatx4){0.f, 0.f, 0.f, 0.f};
#pragma unroll
            for (int kt = 0; kt < 2; kt++) {
                sA[nt] = mfma_bf16(bk[nt][kt], aqA[kt], sA[nt]);
                sB[nt] = mfma_bf16(bk[nt][kt], aqB[kt], sB[nt]);
            }
        }

        if (diag) {
#pragma unroll
            for (int nt = 0; nt < 4; nt++) {
#pragma unroll
                for (int r = 0; r < 4; r++) {
                    const int kvg = kv0 + nt * 16 + q4 * 4 + r;
                    if (kvg > q0A + l16) sA[nt][r] = -3e38f;
                    if (kvg > q0B + l16) sB[nt][r] = -3e38f;
                }
            }
        }

#pragma unroll
        for (int nt = 0; nt < 4; nt++) {
            union { __hip_bfloat16 h[4]; shortx4 s; } uA, uB;
            float pA[4], pB[4];
#pragma unroll
            for (int r = 0; r < 4; r++) {
                pA[r] = fast_exp2(sA[nt][r] * KS_ - MK_);
                pB[r] = fast_exp2(sB[nt][r] * KS_ - MK_);
                uA.h[r] = __float2bfloat16(pA[r]);
                uB.h[r] = __float2bfloat16(pB[r]);
            }
            sumA += (pA[0] + pA[1]) + (pA[2] + pA[3]);
            sumB += (pB[0] + pB[1]) + (pB[2] + pB[3]);
            *(shortx4*)(&plds[wid][0][l16][nt * 16 + q4 * 4]) = uA.s;
            *(shortx4*)(&plds[wid][1][l16][nt * 16 + q4 * 4]) = uB.s;
        }

        lds_fence();

        short8 apA[2], apB[2];
#pragma unroll
        for (int kt = 0; kt < 2; kt++) {
            apA[kt] = *(const short8*)(&plds[wid][0][l16][kt * 32 + q4 * 8]);
            apB[kt] = *(const short8*)(&plds[wid][1][l16][kt * 32 + q4 * 8]);
        }
#pragma unroll
        for (int ct = 0; ct < 4; ct++)
#pragma unroll
            for (int kt = 0; kt < 2; kt++) {
                accA[ct] = mfma_bf16(apA[kt], bv[ct][kt], accA[ct]);
                accB[ct] = mfma_bf16(apB[kt], bv[ct][kt], accB[ct]);
            }

        lds_fence();
    }

    sumA += __shfl_xor(sumA, 16, 64);
    sumA += __shfl_xor(sumA, 32, 64);
    sumB += __shfl_xor(sumB, 16, 64);
    sumB += __shfl_xor(sumB, 32, 64);

    __syncthreads();                               // plds dead; overlay arena
    floatx4* accbuf = (floatx4*)&plds[0][0][0][0];
    float*   lbuf   = (float*)((char*)&plds[0][0][0][0] + 16384);

    auto publish = [&](int slot) {
#pragma unroll
        for (int ct = 0; ct < 4; ct++) {
            accbuf[((slot * 2 + 0) * 4 + ct) * 64 + lane] = accA[ct];
            accbuf[((slot * 2 + 1) * 4 + ct) * 64 + lane] = accB[ct];
        }
        if (q4 == 0) {
            lbuf[(slot * 2 + 0) * 16 + l16] = sumA;
            lbuf[(slot * 2 + 1) * 16 + l16] = sumB;
        }
    };
    auto mergeIn = [&](int slot) {
#pragma unroll
        for (int ct = 0; ct < 4; ct++) {
            accA[ct] += accbuf[((slot * 2 + 0) * 4 + ct) * 64 + lane];
            accB[ct] += accbuf[((slot * 2 + 1) * 4 + ct) * 64 + lane];
        }
        sumA += lbuf[(slot * 2 + 0) * 16 + l16];
        sumB += lbuf[(slot * 2 + 1) * 16 + l16];
    };

    if (wid >= 2) publish(wid - 2);
    __syncthreads();
    if (wid < 2) mergeIn(wid);
    __syncthreads();
    if (wid == 1) publish(0);
    __syncthreads();
    if (wid == 0) {
        mergeIn(0);
        const int orow0 = (bh / NH_) * T_;
        const int hcol  = (bh % NH_) * HD_;
#pragma unroll
        for (int r = 0; r < 4; r++) {
            const float invA = 1.0f / __shfl(sumA, q4 * 4 + r, 64);
            const float invB = 1.0f / __shfl(sumB, q4 * 4 + r, 64);
            __hip_bfloat16* oA = O + (size_t)(orow0 + q0A + q4 * 4 + r) * C_ + hcol;
            __hip_bfloat16* oB = O + (size_t)(orow0 + q0B + q4 * 4 + r) * C_ + hcol;
#pragma unroll
            for (int ct = 0; ct < 4; ct++) {
                oA[ct * 16 + l16] = __float2bfloat16(accA[ct][r] * invA);
                oB[ct * 16 + l16] = __float2bfloat16(accB[ct][r] * invB);
            }
        }
    }
    __syncthreads();   // arena free for next paired tile
}

// ---------- r29 mega-kernel: 4 stages, 3 device-scope barriers, ONE dispatch ----------
// launch_bounds(256,3): VGPR cap ~170 (no spills), 3 blocks/CU guaranteed ->
// NBLK=768 co-resident.
__global__ __launch_bounds__(256, 3) void mega(const float* __restrict__ x,
                                               const float* __restrict__ wqkv,
                                               const float* __restrict__ wproj,
                                               __hip_bfloat16* __restrict__ xb,
                                               __hip_bfloat16* __restrict__ wqkvT,
                                               __hip_bfloat16* __restrict__ wprojT,
                                               __hip_bfloat16* __restrict__ Qall,
                                               __hip_bfloat16* __restrict__ Kall,
                                               __hip_bfloat16* __restrict__ Vt,
                                               __hip_bfloat16* __restrict__ ATT,
                                               float* __restrict__ out,
                                               unsigned int* cnt) {
    __shared__ __align__(16) char arena[32768];

    // phase 0: prep (4224 units, grid-stride)
    for (unsigned u = blockIdx.x; u < 4224u; u += NBLK)
        prep_unit(u, x, wqkv, wproj, xb, wqkvT, wprojT);
    grid_sync(cnt, 1u * NBLK);

    // phase 1: qkv gemm — 576 x (128x128) units, one per block
    if (blockIdx.x < 576u) {
        gemm128_block((int)(blockIdx.x % 18u), (int)(blockIdx.x / 18u),
                      xb, wqkvT, N1_, C_, Qall, Kall, Vt,
                      (__hip_bfloat16*)arena, (__hip_bfloat16*)(arena + 16384));
    }
    grid_sync(cnt, 2u * NBLK);

    // phase 2: attention — pair-balanced units (b, 1535-b): 33 chunks every block
    {
        plds_t* plds = (plds_t*)arena;
        const unsigned u1 = blockIdx.x, u2 = 1535u - blockIdx.x;
        attn_block((int)(u1 % 24u), 63 - (int)(u1 / 24u), Qall, Kall, Vt, ATT, plds);
        attn_block((int)(u2 % 24u), 63 - (int)(u2 / 24u), Qall, Kall, Vt, ATT, plds);
    }
    grid_sync(cnt, 3u * NBLK);

    // phase 3: out proj — 768 x (64x64) units, exactly one per block
    gemm64_block((int)(blockIdx.x % 12u), (int)(blockIdx.x / 12u),
                 ATT, wprojT, C_, C_, out,
                 (__hip_bfloat16*)arena, (__hip_bfloat16*)(arena + 5120));
}

// ---------- fallback-path kernels (thin wrappers; unchanged behavior) ----------
__global__ __launch_bounds__(256) void prep1(const float* __restrict__ x,
                                             const float* __restrict__ wqkv,
                                             __hip_bfloat16* __restrict__ xb,
                                             __hip_bfloat16* __restrict__ wqkvT) {
    if (blockIdx.x < 3072) {
        const int idx = blockIdx.x * 256 + threadIdx.x;
        const floatx4 v = ((const floatx4*)x)[idx];
        union { __hip_bfloat16 h[4]; shortx4 s; } u;
#pragma unroll
        for (int j = 0; j < 4; j++) u.h[j] = __float2bfloat16(v[j]);
        ((shortx4*)xb)[idx] = u.s;
    } else {
        const int j  = (blockIdx.x - 3072) * 256 + threadIdx.x;
        const int k8 = j / N1_;
        const int n  = j - k8 * N1_;
        union { __hip_bfloat16 h[8]; short8 s; } u;
#pragma unroll
        for (int jj = 0; jj < 8; jj++)
            u.h[jj] = __float2bfloat16(wqkv[(size_t)(k8 * 8 + jj) * N1_ + n]);
        *(short8*)(wqkvT + (size_t)n * C_ + k8 * 8) = u.s;
    }
}
__global__ __launch_bounds__(256) void prep2(const float* __restrict__ wproj,
                                             __hip_bfloat16* __restrict__ wprojT) {
    const int j  = blockIdx.x * 256 + threadIdx.x;
    const int k8 = j / C_;
    const int n  = j - k8 * C_;
    union { __hip_bfloat16 h[8]; short8 s; } u;
#pragma unroll
    for (int jj = 0; jj < 8; jj++)
        u.h[jj] = __float2bfloat16(wproj[(size_t)(k8 * 8 + jj) * C_ + n]);
    *(short8*)(wprojT + (size_t)n * C_ + k8 * 8) = u.s;
}
__global__ __launch_bounds__(256) void gemm_bt128(const __hip_bfloat16* __restrict__ A,
                                                  const __hip_bfloat16* __restrict__ Bt,
                                                  int N, int K,
                                                  __hip_bfloat16* __restrict__ O0,
                                                  __hip_bfloat16* __restrict__ O1,
                                                  __hip_bfloat16* __restrict__ O2) {
    __shared__ __align__(16) char ar[32768];
    gemm128_block(blockIdx.x, blockIdx.y, A, Bt, N, K, O0, O1, O2,
                  (__hip_bfloat16*)ar, (__hip_bfloat16*)(ar + 16384));
}
__global__ __launch_bounds__(256) void gemm_bt64(const __hip_bfloat16* __restrict__ A,
                                                 const __hip_bfloat16* __restrict__ Bt,
                                                 int N, int K,
                                                 float* __restrict__ O0) {
    __shared__ __align__(16) char ar[10240];
    gemm64_block(blockIdx.x, blockIdx.y, A, Bt, N, K, O0,
                 (__hip_bfloat16*)ar, (__hip_bfloat16*)(ar + 5120));
}
__global__ __launch_bounds__(256) void attn_fused(const __hip_bfloat16* __restrict__ Q,
                                                  const __hip_bfloat16* __restrict__ Kd,
                                                  const __hip_bfloat16* __restrict__ Vt,
                                                  __hip_bfloat16* __restrict__ O) {
    __shared__ __align__(16) char ar[18432];
    attn_block(blockIdx.x, 63 - (int)blockIdx.y, Q, Kd, Vt, O, (plds_t*)ar);
}

extern "C" void kernel_launch(void* const* d_in, const int* in_sizes, int n_in,
                              void* d_out, int out_size, void* d_ws, size_t ws_size,
                              hipStream_t stream) {
    const float *x = nullptr, *wqkv = nullptr, *wproj = nullptr;
    for (int i = 0; i < n_in; i++) {
        const int s = in_sizes[i];
        if (s == M_ * C_ && !x) x = (const float*)d_in[i];
        else if (s == C_ * N1_ && !wqkv) wqkv = (const float*)d_in[i];
        else if (s == C_ * C_ && !wproj) wproj = (const float*)d_in[i];
    }
    float* out = (float*)d_out;
    __hip_bfloat16* ws = (__hip_bfloat16*)d_ws;
    __hip_bfloat16* Vt = (__hip_bfloat16*)d_out;       // d_out lower half (bf16)

    // r13/14-proven aliasing chain within ws + d_out.
    __hip_bfloat16* Qall  = ws;
    __hip_bfloat16* Kall  = Qall + 2 * PB_;
    __hip_bfloat16* ATT   = Kall + 2 * PB_;
    __hip_bfloat16* xb    = ATT;
    __hip_bfloat16* wqkvT = (__hip_bfloat16*)d_out + 2 * PB_;

    const size_t needMerged = (6 * PB_ + (size_t)C_ * C_) * sizeof(__hip_bfloat16);  // 20,054,016
    if (ws_size >= needMerged) {   // r19-proven: this path runs (ws >= 20.05 MB)
        __hip_bfloat16* wprojT = ws + 6 * PB_;
        // barrier counter in the LAST 64B of d_out: untouched by Vt/wqkvT/ATT,
        // overwritten by phase-3 output only AFTER the final barrier; re-zeroed
        // here every launch (hipMemsetAsync is graph-capture-safe).
        unsigned int* cnt = (unsigned int*)((char*)d_out + (size_t)M_ * C_ * 4 - 64);
        (void)hipMemsetAsync(cnt, 0, 64, stream);
        mega<<<dim3(NBLK), 256, 0, stream>>>(x, wqkv, wproj, xb, wqkvT, wprojT,
                                             Qall, Kall, Vt, ATT, out, cnt);
    } else {
        __hip_bfloat16* wprojT = Qall;
        prep1<<<dim3(3936), 256, 0, stream>>>(x, wqkv, xb, wqkvT);
        gemm_bt128<<<dim3(N1_ / 128, M_ / 128), 256, 0, stream>>>(
            xb, wqkvT, N1_, C_, Qall, Kall, Vt);
        attn_fused<<<dim3(2 * NH_, 64), 256, 0, stream>>>(Qall, Kall, Vt, ATT);
        prep2<<<dim3(288), 256, 0, stream>>>(wproj, wprojT);
        gemm_bt64<<<dim3(C_ / 64, M_ / 64), 256, 0, stream>>>(ATT, wprojT, C_, C_, out);
    }
}